// Round 4
// baseline (200.257 us; speedup 1.0000x reference)
//
#include <hip/hip_runtime.h>

#define Bb 4
#define Tt 64
#define Nn 16
#define Mm 8
#define Dd 512
#define RR 32      // Bb*Mm rows per (t,n) group
#define QSTR 536   // padded LDS row stride in u16: holds 528 (x,1,pad) cols;
                   // 536*2=1072 B = 268 dw == 12 mod 32 -> b128 reads conflict-free
#define VOFF 270336  // u16 offset of Wv region in workspace (16*33*512)

typedef __attribute__((ext_vector_type(8))) short bf16x8;
typedef __attribute__((ext_vector_type(16))) float f32x16;

__device__ __forceinline__ unsigned short f2bf(float f) {
    union { float f; unsigned int u; } v; v.f = f;
    unsigned int r = (v.u + 0x7fffu + ((v.u >> 16) & 1u)) >> 16;  // RNE
    return (unsigned short)r;
}
__device__ __forceinline__ float bf2f(unsigned short h) {
    union { unsigned int u; float f; } v; v.u = ((unsigned int)h) << 16;
    return v.f;
}

// ---- Single pack kernel, grid 512 x 256 threads ----
// Blocks 0..255  : tile (dT = blk>>4, eT = blk&15) of Atilde = Wq^T @ Wk via
//                  MFMA (4 waves split K=512, LDS tree-reduce), written in
//                  B-fragment order; dT==0 blocks also build the ck (kk=32)
//                  bias fragment (ck = Wk^T bq).
// Blocks 256..511: Wv -> bf16 B-fragment order at VOFF (output-driven,
//                  coalesced stores).
__global__ __launch_bounds__(256) void pack_kernel(
    const float* __restrict__ Wq, const float* __restrict__ Wk,
    const float* __restrict__ Wv, const float* __restrict__ bq,
    unsigned short* __restrict__ Wb)
{
    const int tid = threadIdx.x;
    if (blockIdx.x >= 256) {
        int idx = (blockIdx.x - 256) * 256 + tid;   // 65536 ushort4
        int o = idx << 2;
        int j  = o & 7;
        int n  = (o >> 3) & 31;
        int hi = (o >> 8) & 1;
        int ekk = o >> 9;            // e*32+kk
        int kk = ekk & 31;
        int e  = ekk >> 5;           // 0..15
        int row = e * 32 + n;
        int d = kk * 16 + hi * 8 + j;
        float4 v = *(const float4*)(Wv + row * Dd + d);
        ushort4 o4;
        o4.x = f2bf(v.x); o4.y = f2bf(v.y); o4.z = f2bf(v.z); o4.w = f2bf(v.w);
        *(ushort4*)(Wb + VOFF + o) = o4;
        return;
    }

    const int eT = blockIdx.x & 15;
    const int dT = blockIdx.x >> 4;
    const int wave = tid >> 6, lane = tid & 63;
    const int arow = lane & 31, h = lane >> 5;

    // D[d'][e'] = sum_n bf(Wq[n][dT*32+d']) * bf(Wk[n][eT*32+e'])
    f32x16 acc;
    #pragma unroll
    for (int r = 0; r < 16; ++r) acc[r] = 0.f;

    #pragma unroll
    for (int s = 0; s < 8; ++s) {            // wave w owns K chunk [w*128, w*128+128)
        int n0 = (wave * 8 + s) * 16;
        bf16x8 af, bfr;
        #pragma unroll
        for (int j = 0; j < 8; ++j) {
            int n = n0 + h * 8 + j;
            af[j]  = (short)f2bf(Wq[n * Dd + dT * 32 + arow]);
            bfr[j] = (short)f2bf(Wk[n * Dd + eT * 32 + arow]);
        }
        acc = __builtin_amdgcn_mfma_f32_32x32x16_bf16(af, bfr, acc, 0, 0, 0);
    }

    __shared__ float red[4][1024];
    #pragma unroll
    for (int r = 0; r < 16; ++r) {
        int row = (r & 3) + 8 * (r >> 2) + 4 * h;          // d'
        red[wave][row * 32 + arow] = acc[r];
    }
    __syncthreads();

    #pragma unroll
    for (int i = 0; i < 4; ++i) {
        int el = i * 256 + tid;              // d'*32 + e'
        int dp = el >> 5, ep = el & 31;
        float v = red[0][el] + red[1][el] + red[2][el] + red[3][el];
        int d = dT * 32 + dp;
        int kkg = d >> 4, hh = (d >> 3) & 1, jj = d & 7;
        Wb[(long)(eT * 33 + kkg) * 512 + ((hh * 32 + ep) << 3) + jj] = f2bf(v);
    }

    if (dT == 0) {
        // ck[e'] = sum_n bf(Wk[n][eT*32+e']) * bq[n]; 8 strips of 64 n's
        int ep = tid & 31, strip = tid >> 5;
        float c = 0.f;
        #pragma unroll 8
        for (int n = strip * 64; n < strip * 64 + 64; ++n)
            c += bf2f(f2bf(Wk[n * Dd + eT * 32 + ep])) * bq[n];
        __syncthreads();                     // red reads above all done
        red[0][tid] = c;                     // tid = strip*32 + ep
        long b32 = (long)(eT * 33 + 32) << 9;
        Wb[b32 + tid] = 0; Wb[b32 + 256 + tid] = 0;   // zero bias fragment
        __syncthreads();
        if (tid < 32) {
            float s = 0.f;
            #pragma unroll
            for (int k = 0; k < 8; ++k) s += red[0][k * 32 + tid];
            Wb[b32 + (tid << 3)] = f2bf(s);  // col=tid, h=0, j=0 slot
        }
    }
}

// One block per TWO (t,n) groups. 1024 threads = 16 waves, 2 blocks/CU
// (launch_bounds(1024,8) pins VGPR<=64).
// Chain: P1 stage -> P2a: Y = x~@[Atilde;ck] -> P3 scores (fold-reduce) ->
//        P2b: Z = x~@Wv^T (independent of scores; absorbs barrier latency) ->
//        bar -> P4 softmax -> bar -> combine out = P@Z + bv from registers.
// V-algebra: out = P@(x@Wv^T) + bv (softmax rows sum to 1; Z stays f32).
__global__ __launch_bounds__(1024, 8) void fused_attn_kernel(
    const float* __restrict__ x, const unsigned short* __restrict__ Wb,
    const float* __restrict__ bv, float* __restrict__ out)
{
    __shared__ unsigned short lds_x[2][RR * QSTR];  // 68,608 B (x~, bf16)
    __shared__ float lds_s[2][64];                  // scores -> probs

    const int tid = threadIdx.x;
    const int lane = tid & 63;
    const int wave = tid >> 6;       // 0..15
    const int arow = lane & 31;
    const int ahalf = lane >> 5;
    const int l5 = lane & 31;

    const int gi0 = blockIdx.x << 1;
    const int t = gi0 >> 4;
    const int n0 = gi0 & 15;
    const int rot = (blockIdx.x * 7) & 31;   // decorrelate L2 address streams

    // B~ fragment base for this wave's e-tile (33 kk-fragments of 512 u16)
    const unsigned short* wb = Wb + (long)wave * (33 * 512) + (lane << 3);
    #define KOF(s) ((s) + rot >= 32 ? (s) + rot - 32 : (s) + rot)

    bf16x8 pf[4];
    #pragma unroll
    for (int i = 0; i < 4; ++i)
        pf[i] = *(const bf16x8*)(wb + KOF(i) * 512);

    if (tid < 128) lds_s[tid >> 6][tid & 63] = 0.f;

    // ---- Phase 1: stage x~ (bf16) ----
    #pragma unroll
    for (int i = 0; i < 8; ++i) {
        int fi = i * 1024 + tid;     // 8192 float4
        int g = fi >> 12;
        int rem = fi & 4095;
        int row = rem >> 7;
        int d = (rem & 127) << 2;
        int b = row >> 3, m = row & 7;
        float4 v = *(const float4*)(x + ((((long)(b * Tt + t)) * Nn + (n0 + g)) * Mm + m) * Dd + d);
        ushort4 o;
        o.x = f2bf(v.x); o.y = f2bf(v.y); o.z = f2bf(v.z); o.w = f2bf(v.w);
        *(ushort4*)(&lds_x[g][row * QSTR + d]) = o;
    }
    if (tid < 64) {                  // bias column: x~[row][512]=1, 513..527=0
        int g = tid >> 5, row = tid & 31;
        unsigned short* p = &lds_x[g][row * QSTR + 512];
        ushort4 one = {0x3F80, 0, 0, 0}, zz = {0, 0, 0, 0};
        *(ushort4*)(p) = one; *(ushort4*)(p + 4) = zz;
        *(ushort4*)(p + 8) = zz; *(ushort4*)(p + 12) = zz;
    }
    __syncthreads();

    // ---- Phase 2a: Y = x~ @ B~  (K = 33 steps of 16) ----
    const unsigned short* abase0 = &lds_x[0][arow * QSTR + (ahalf << 3)];
    const unsigned short* abase1 = &lds_x[1][arow * QSTR + (ahalf << 3)];

    f32x16 aY0, aY1;
    #pragma unroll
    for (int r = 0; r < 16; ++r) { aY0[r] = 0.f; aY1[r] = 0.f; }

    #pragma unroll
    for (int s = 0; s < 33; ++s) {
        int kk = (s < 32) ? KOF(s) : 32;
        bf16x8 bf = pf[s & 3];
        if (s + 4 <= 32) {
            int kn = (s + 4 < 32) ? KOF(s + 4) : 32;
            pf[s & 3] = *(const bf16x8*)(wb + kn * 512);
        }
        bf16x8 a0 = *(const bf16x8*)(abase0 + kk * 16);
        bf16x8 a1 = *(const bf16x8*)(abase1 + kk * 16);
        aY0 = __builtin_amdgcn_mfma_f32_32x32x16_bf16(a0, bf, aY0, 0, 0, 0);
        aY1 = __builtin_amdgcn_mfma_f32_32x32x16_bf16(a1, bf, aY1, 0, 0, 0);
    }

    // Wv prefetch issued before P3: lands while the score fold runs
    const unsigned short* vb = Wb + VOFF + ((long)wave << 14) + (lane << 3);
    bf16x8 pv[4];
    pv[0] = *(const bf16x8*)(vb + ((0 + rot) & 31) * 512);
    pv[1] = *(const bf16x8*)(vb + ((1 + rot) & 31) * 512);
    pv[2] = *(const bf16x8*)(vb + ((2 + rot) & 31) * 512);
    pv[3] = *(const bf16x8*)(vb + ((3 + rot) & 31) * 512);

    // ---- Phase 3: fold-reduce scores. Lane holds Y[b=r>>2][m=(r&3)+4h] at
    // e = 32*wave + l5. 5-step fold aligns idx-bit s with lane-bit s ->
    // lane l5 ends with (k=l5&7, mm=l5>>3), m = mm+4*ahalf.
    const int ecol = (wave << 5) + l5;
    #pragma unroll
    for (int g = 0; g < 2; ++g) {
        const f32x16& aY = g ? aY1 : aY0;
        float p[32];
        #pragma unroll
        for (int i = 0; i < 32; ++i) p[i] = 0.f;
        #pragma unroll
        for (int b = 0; b < 4; ++b) {
            float xc[8];
            #pragma unroll
            for (int k = 0; k < 8; ++k)
                xc[k] = bf2f(lds_x[g][(b * 8 + k) * QSTR + ecol]);
            #pragma unroll
            for (int mm = 0; mm < 4; ++mm) {
                float yv = aY[b * 4 + mm];
                #pragma unroll
                for (int k = 0; k < 8; ++k) p[mm * 8 + k] += yv * xc[k];
            }
        }
        const bool b0 = (lane & 1) != 0;
        const bool b1 = (lane & 2) != 0;
        const bool b2 = (lane & 4) != 0;
        const bool b3 = (lane & 8) != 0;
        const bool b4 = (lane & 16) != 0;
        float q16[16];
        #pragma unroll
        for (int i = 0; i < 16; ++i) {
            float keep = b0 ? p[2 * i + 1] : p[2 * i];
            float send = b0 ? p[2 * i] : p[2 * i + 1];
            q16[i] = keep + __shfl_xor(send, 1);
        }
        float q8[8];
        #pragma unroll
        for (int i = 0; i < 8; ++i) {
            float keep = b1 ? q16[2 * i + 1] : q16[2 * i];
            float send = b1 ? q16[2 * i] : q16[2 * i + 1];
            q8[i] = keep + __shfl_xor(send, 2);
        }
        float q4[4];
        #pragma unroll
        for (int i = 0; i < 4; ++i) {
            float keep = b2 ? q8[2 * i + 1] : q8[2 * i];
            float send = b2 ? q8[2 * i] : q8[2 * i + 1];
            q4[i] = keep + __shfl_xor(send, 4);
        }
        float q2[2];
        #pragma unroll
        for (int i = 0; i < 2; ++i) {
            float keep = b3 ? q4[2 * i + 1] : q4[2 * i];
            float send = b3 ? q4[2 * i] : q4[2 * i + 1];
            q2[i] = keep + __shfl_xor(send, 8);
        }
        float sval = (b4 ? q2[1] : q2[0]) + __shfl_xor(b4 ? q2[0] : q2[1], 16);
        int k = l5 & 7, mm = l5 >> 3;
        int m = mm + 4 * ahalf;
        atomicAdd(&lds_s[g][m * 8 + k], sval);
    }

    // ---- Phase 2b: Z = x~ @ Wv^T (no score dependency; runs under barrier) ----
    f32x16 aZ0, aZ1;
    #pragma unroll
    for (int r = 0; r < 16; ++r) { aZ0[r] = 0.f; aZ1[r] = 0.f; }
    #pragma unroll
    for (int s = 0; s < 32; ++s) {
        int kk = (s + rot) & 31;
        bf16x8 wvf = pv[s & 3];
        if (s + 4 < 32) pv[s & 3] = *(const bf16x8*)(vb + (((s + 4 + rot) & 31)) * 512);
        bf16x8 a0 = *(const bf16x8*)(abase0 + kk * 16);
        bf16x8 a1 = *(const bf16x8*)(abase1 + kk * 16);
        aZ0 = __builtin_amdgcn_mfma_f32_32x32x16_bf16(a0, wvf, aZ0, 0, 0, 0);
        aZ1 = __builtin_amdgcn_mfma_f32_32x32x16_bf16(a1, wvf, aZ1, 0, 0, 0);
    }
    __syncthreads();                 // all P3 atomics complete

    // ---- Phase 4: softmax over k per (g,m) ----
    if (tid < 128) {
        int g = tid >> 6;
        int p = tid & 63;
        float s = lds_s[g][p] * 0.04419417382415922f;   // 1/sqrt(512)
        float mx = s;
        mx = fmaxf(mx, __shfl_xor(mx, 1));
        mx = fmaxf(mx, __shfl_xor(mx, 2));
        mx = fmaxf(mx, __shfl_xor(mx, 4));
        float e = __expf(s - mx);
        float sum = e;
        sum += __shfl_xor(sum, 1);
        sum += __shfl_xor(sum, 2);
        sum += __shfl_xor(sum, 4);
        lds_s[g][p] = e / sum;
    }
    __syncthreads();

    // ---- Phase 5: out[b,m,f] = sum_k P[m,k] Z[b,k,f] + bv[f], in registers ----
    // Z accumulator rows: mrow = (r&3)+8*(r>>2)+4*ahalf = b*8 + kv, so this
    // half holds kv in [4*ahalf, 4*ahalf+4); other half's kv via shfl_xor 32.
    {
        int f = (wave << 5) + arow;
        float bvv = bv[f];
        float* o0 = out + f;
        #pragma unroll
        for (int g = 0; g < 2; ++g) {
            const f32x16& z = g ? aZ1 : aZ0;
            float zs[16];
            #pragma unroll
            for (int r = 0; r < 16; ++r) zs[r] = __shfl_xor(z[r], 32);
            #pragma unroll
            for (int j = 0; j < 4; ++j) {
                int m = j + 4 * ahalf;
                float4 pA = *(const float4*)&lds_s[g][m * 8 + 4 * ahalf];
                float4 pB = *(const float4*)&lds_s[g][m * 8 + 4 * (1 - ahalf)];
                #pragma unroll
                for (int b = 0; b < 4; ++b) {
                    int r0 = 4 * b;
                    float o = pA.x * z[r0]  + pA.y * z[r0 + 1]
                            + pA.z * z[r0 + 2] + pA.w * z[r0 + 3]
                            + pB.x * zs[r0] + pB.y * zs[r0 + 1]
                            + pB.z * zs[r0 + 2] + pB.w * zs[r0 + 3];
                    long base = ((((long)(b * Tt + t)) * Nn + (n0 + g)) * Mm + m) * Dd;
                    o0[base] = o + bvv;
                }
            }
        }
    }
    #undef KOF
}

extern "C" void kernel_launch(void* const* d_in, const int* in_sizes, int n_in,
                              void* d_out, int out_size, void* d_ws, size_t ws_size,
                              hipStream_t stream) {
    const float* x  = (const float*)d_in[0];
    const float* Wq = (const float*)d_in[1];
    const float* bq = (const float*)d_in[2];
    const float* Wk = (const float*)d_in[3];
    const float* Wv = (const float*)d_in[5];
    const float* bv = (const float*)d_in[6];
    float* out = (float*)d_out;
    unsigned short* Wb = (unsigned short*)d_ws;   // B~ (540KB) + Wv (512KB) frags

    pack_kernel<<<512, 256, 0, stream>>>(Wq, Wk, Wv, bq, Wb);
    fused_attn_kernel<<<Tt * Nn / 2, 1024, 0, stream>>>(x, Wb, bv, out);
}

// Round 5
// 171.823 us; speedup vs baseline: 1.1655x; 1.1655x over previous
//
#include <hip/hip_runtime.h>

#define Bb 4
#define Tt 64
#define Nn 16
#define Mm 8
#define Dd 512
#define RR 32      // Bb*Mm rows per (t,n) group
#define QSTR 536   // padded LDS row stride in u16: holds 528 (x,1,pad) cols;
                   // 536*2=1072 B = 268 dw == 12 mod 32 -> b128 reads conflict-free
#define VOFF 270336  // u16 offset of Wv region in workspace (16*33*512)

typedef __attribute__((ext_vector_type(8))) short bf16x8;
typedef __attribute__((ext_vector_type(16))) float f32x16;

__device__ __forceinline__ unsigned short f2bf(float f) {
    union { float f; unsigned int u; } v; v.f = f;
    unsigned int r = (v.u + 0x7fffu + ((v.u >> 16) & 1u)) >> 16;  // RNE
    return (unsigned short)r;
}
__device__ __forceinline__ float bf2f(unsigned short h) {
    union { unsigned int u; float f; } v; v.u = ((unsigned int)h) << 16;
    return v.f;
}

// ---- Single pack kernel, grid 512 x 256 threads ----
// Blocks 0..255  : tile (dT = blk>>4, eT = blk&15) of Atilde = Wq^T @ Wk via
//                  MFMA (4 waves split K=512, LDS tree-reduce), written in
//                  B-fragment order; dT==0 blocks also build the ck (kk=32)
//                  bias fragment (ck = Wk^T bq).
// Blocks 256..511: Wv -> bf16 B-fragment order at VOFF (output-driven,
//                  coalesced stores).
__global__ __launch_bounds__(256) void pack_kernel(
    const float* __restrict__ Wq, const float* __restrict__ Wk,
    const float* __restrict__ Wv, const float* __restrict__ bq,
    unsigned short* __restrict__ Wb)
{
    const int tid = threadIdx.x;
    if (blockIdx.x >= 256) {
        int idx = (blockIdx.x - 256) * 256 + tid;   // 65536 ushort4
        int o = idx << 2;
        int j  = o & 7;
        int n  = (o >> 3) & 31;
        int hi = (o >> 8) & 1;
        int ekk = o >> 9;            // e*32+kk
        int kk = ekk & 31;
        int e  = ekk >> 5;           // 0..15
        int row = e * 32 + n;
        int d = kk * 16 + hi * 8 + j;
        float4 v = *(const float4*)(Wv + row * Dd + d);
        ushort4 o4;
        o4.x = f2bf(v.x); o4.y = f2bf(v.y); o4.z = f2bf(v.z); o4.w = f2bf(v.w);
        *(ushort4*)(Wb + VOFF + o) = o4;
        return;
    }

    const int eT = blockIdx.x & 15;
    const int dT = blockIdx.x >> 4;
    const int wave = tid >> 6, lane = tid & 63;
    const int arow = lane & 31, h = lane >> 5;

    // D[d'][e'] = sum_n bf(Wq[n][dT*32+d']) * bf(Wk[n][eT*32+e'])
    f32x16 acc;
    #pragma unroll
    for (int r = 0; r < 16; ++r) acc[r] = 0.f;

    #pragma unroll
    for (int s = 0; s < 8; ++s) {            // wave w owns K chunk [w*128, w*128+128)
        int n0 = (wave * 8 + s) * 16;
        bf16x8 af, bfr;
        #pragma unroll
        for (int j = 0; j < 8; ++j) {
            int n = n0 + h * 8 + j;
            af[j]  = (short)f2bf(Wq[n * Dd + dT * 32 + arow]);
            bfr[j] = (short)f2bf(Wk[n * Dd + eT * 32 + arow]);
        }
        acc = __builtin_amdgcn_mfma_f32_32x32x16_bf16(af, bfr, acc, 0, 0, 0);
    }

    __shared__ float red[4][1024];
    #pragma unroll
    for (int r = 0; r < 16; ++r) {
        int row = (r & 3) + 8 * (r >> 2) + 4 * h;          // d'
        red[wave][row * 32 + arow] = acc[r];
    }
    __syncthreads();

    #pragma unroll
    for (int i = 0; i < 4; ++i) {
        int el = i * 256 + tid;              // d'*32 + e'
        int dp = el >> 5, ep = el & 31;
        float v = red[0][el] + red[1][el] + red[2][el] + red[3][el];
        int d = dT * 32 + dp;
        int kkg = d >> 4, hh = (d >> 3) & 1, jj = d & 7;
        Wb[(long)(eT * 33 + kkg) * 512 + ((hh * 32 + ep) << 3) + jj] = f2bf(v);
    }

    if (dT == 0) {
        // ck[e'] = sum_n bf(Wk[n][eT*32+e']) * bq[n]; 8 strips of 64 n's
        int ep = tid & 31, strip = tid >> 5;
        float c = 0.f;
        #pragma unroll 8
        for (int n = strip * 64; n < strip * 64 + 64; ++n)
            c += bf2f(f2bf(Wk[n * Dd + eT * 32 + ep])) * bq[n];
        __syncthreads();                     // red reads above all done
        red[0][tid] = c;                     // tid = strip*32 + ep
        long b32 = (long)(eT * 33 + 32) << 9;
        Wb[b32 + tid] = 0; Wb[b32 + 256 + tid] = 0;   // zero bias fragment
        __syncthreads();
        if (tid < 32) {
            float s = 0.f;
            #pragma unroll
            for (int k = 0; k < 8; ++k) s += red[0][k * 32 + tid];
            Wb[b32 + (tid << 3)] = f2bf(s);  // col=tid, h=0, j=0 slot
        }
    }
}

// One block per TWO (t,n) groups. 1024 threads = 16 waves.
// launch_bounds(1024,4): R4's (1024,8) forced a 64-reg budget -> accumulator
// scratch spills (+110MB write traffic). (1024,4) lets regalloc settle (~48-70);
// if <=64, 2 blocks/CU co-residency is preserved.
// Chain: P1 stage -> P2a: Y = x~@[Atilde;ck] -> P3 scores (fold-reduce) ->
//        P2b: Z = x~@Wv^T (independent of scores; absorbs barrier latency) ->
//        bar -> P4 softmax -> bar -> combine out = P@Z + bv from registers.
// V-algebra: out = P@(x@Wv^T) + bv (softmax rows sum to 1; Z stays f32).
__global__ __launch_bounds__(1024, 4) void fused_attn_kernel(
    const float* __restrict__ x, const unsigned short* __restrict__ Wb,
    const float* __restrict__ bv, float* __restrict__ out)
{
    __shared__ unsigned short lds_x[2][RR * QSTR];  // 68,608 B (x~, bf16)
    __shared__ float lds_s[2][64];                  // scores -> probs

    const int tid = threadIdx.x;
    const int lane = tid & 63;
    const int wave = tid >> 6;       // 0..15
    const int arow = lane & 31;
    const int ahalf = lane >> 5;
    const int l5 = lane & 31;

    const int gi0 = blockIdx.x << 1;
    const int t = gi0 >> 4;
    const int n0 = gi0 & 15;
    const int rot = (blockIdx.x * 7) & 31;   // decorrelate L2 address streams

    // B~ fragment base for this wave's e-tile (33 kk-fragments of 512 u16)
    const unsigned short* wb = Wb + (long)wave * (33 * 512) + (lane << 3);
    #define KOF(s) ((s) + rot >= 32 ? (s) + rot - 32 : (s) + rot)

    bf16x8 pf[4];
    #pragma unroll
    for (int i = 0; i < 4; ++i)
        pf[i] = *(const bf16x8*)(wb + KOF(i) * 512);

    if (tid < 128) lds_s[tid >> 6][tid & 63] = 0.f;

    // ---- Phase 1: stage x~ (bf16) ----
    #pragma unroll
    for (int i = 0; i < 8; ++i) {
        int fi = i * 1024 + tid;     // 8192 float4
        int g = fi >> 12;
        int rem = fi & 4095;
        int row = rem >> 7;
        int d = (rem & 127) << 2;
        int b = row >> 3, m = row & 7;
        float4 v = *(const float4*)(x + ((((long)(b * Tt + t)) * Nn + (n0 + g)) * Mm + m) * Dd + d);
        ushort4 o;
        o.x = f2bf(v.x); o.y = f2bf(v.y); o.z = f2bf(v.z); o.w = f2bf(v.w);
        *(ushort4*)(&lds_x[g][row * QSTR + d]) = o;
    }
    if (tid < 64) {                  // bias column: x~[row][512]=1, 513..527=0
        int g = tid >> 5, row = tid & 31;
        unsigned short* p = &lds_x[g][row * QSTR + 512];
        ushort4 one = {0x3F80, 0, 0, 0}, zz = {0, 0, 0, 0};
        *(ushort4*)(p) = one; *(ushort4*)(p + 4) = zz;
        *(ushort4*)(p + 8) = zz; *(ushort4*)(p + 12) = zz;
    }
    __syncthreads();

    // ---- Phase 2a: Y = x~ @ B~  (K = 33 steps of 16) ----
    const unsigned short* abase0 = &lds_x[0][arow * QSTR + (ahalf << 3)];
    const unsigned short* abase1 = &lds_x[1][arow * QSTR + (ahalf << 3)];

    f32x16 aY0, aY1;
    #pragma unroll
    for (int r = 0; r < 16; ++r) { aY0[r] = 0.f; aY1[r] = 0.f; }

    #pragma unroll
    for (int s = 0; s < 33; ++s) {
        int kk = (s < 32) ? KOF(s) : 32;
        bf16x8 bf = pf[s & 3];
        if (s + 4 <= 32) {
            int kn = (s + 4 < 32) ? KOF(s + 4) : 32;
            pf[s & 3] = *(const bf16x8*)(wb + kn * 512);
        }
        bf16x8 a0 = *(const bf16x8*)(abase0 + kk * 16);
        bf16x8 a1 = *(const bf16x8*)(abase1 + kk * 16);
        aY0 = __builtin_amdgcn_mfma_f32_32x32x16_bf16(a0, bf, aY0, 0, 0, 0);
        aY1 = __builtin_amdgcn_mfma_f32_32x32x16_bf16(a1, bf, aY1, 0, 0, 0);
    }

    // Wv prefetch issued before P3: lands while the score fold runs
    const unsigned short* vb = Wb + VOFF + ((long)wave << 14) + (lane << 3);
    bf16x8 pv[4];
    pv[0] = *(const bf16x8*)(vb + ((0 + rot) & 31) * 512);
    pv[1] = *(const bf16x8*)(vb + ((1 + rot) & 31) * 512);
    pv[2] = *(const bf16x8*)(vb + ((2 + rot) & 31) * 512);
    pv[3] = *(const bf16x8*)(vb + ((3 + rot) & 31) * 512);

    // ---- Phase 3: fold-reduce scores. Lane holds Y[b=r>>2][m=(r&3)+4h] at
    // e = 32*wave + l5. 5-step fold aligns idx-bit s with lane-bit s ->
    // lane l5 ends with (k=l5&7, mm=l5>>3), m = mm+4*ahalf.
    const int ecol = (wave << 5) + l5;
    #pragma unroll
    for (int g = 0; g < 2; ++g) {
        const f32x16& aY = g ? aY1 : aY0;
        float p[32];
        #pragma unroll
        for (int i = 0; i < 32; ++i) p[i] = 0.f;
        #pragma unroll
        for (int b = 0; b < 4; ++b) {
            float xc[8];
            #pragma unroll
            for (int k = 0; k < 8; ++k)
                xc[k] = bf2f(lds_x[g][(b * 8 + k) * QSTR + ecol]);
            #pragma unroll
            for (int mm = 0; mm < 4; ++mm) {
                float yv = aY[b * 4 + mm];
                #pragma unroll
                for (int k = 0; k < 8; ++k) p[mm * 8 + k] += yv * xc[k];
            }
        }
        const bool b0 = (lane & 1) != 0;
        const bool b1 = (lane & 2) != 0;
        const bool b2 = (lane & 4) != 0;
        const bool b3 = (lane & 8) != 0;
        const bool b4 = (lane & 16) != 0;
        float q16[16];
        #pragma unroll
        for (int i = 0; i < 16; ++i) {
            float keep = b0 ? p[2 * i + 1] : p[2 * i];
            float send = b0 ? p[2 * i] : p[2 * i + 1];
            q16[i] = keep + __shfl_xor(send, 1);
        }
        float q8[8];
        #pragma unroll
        for (int i = 0; i < 8; ++i) {
            float keep = b1 ? q16[2 * i + 1] : q16[2 * i];
            float send = b1 ? q16[2 * i] : q16[2 * i + 1];
            q8[i] = keep + __shfl_xor(send, 2);
        }
        float q4[4];
        #pragma unroll
        for (int i = 0; i < 4; ++i) {
            float keep = b2 ? q8[2 * i + 1] : q8[2 * i];
            float send = b2 ? q8[2 * i] : q8[2 * i + 1];
            q4[i] = keep + __shfl_xor(send, 4);
        }
        float q2[2];
        #pragma unroll
        for (int i = 0; i < 2; ++i) {
            float keep = b3 ? q4[2 * i + 1] : q4[2 * i];
            float send = b3 ? q4[2 * i] : q4[2 * i + 1];
            q2[i] = keep + __shfl_xor(send, 8);
        }
        float sval = (b4 ? q2[1] : q2[0]) + __shfl_xor(b4 ? q2[0] : q2[1], 16);
        int k = l5 & 7, mm = l5 >> 3;
        int m = mm + 4 * ahalf;
        atomicAdd(&lds_s[g][m * 8 + k], sval);
    }

    // ---- Phase 2b: Z = x~ @ Wv^T (no score dependency; runs under barrier) ----
    f32x16 aZ0, aZ1;
    #pragma unroll
    for (int r = 0; r < 16; ++r) { aZ0[r] = 0.f; aZ1[r] = 0.f; }
    #pragma unroll
    for (int s = 0; s < 32; ++s) {
        int kk = (s + rot) & 31;
        bf16x8 wvf = pv[s & 3];
        if (s + 4 < 32) pv[s & 3] = *(const bf16x8*)(vb + (((s + 4 + rot) & 31)) * 512);
        bf16x8 a0 = *(const bf16x8*)(abase0 + kk * 16);
        bf16x8 a1 = *(const bf16x8*)(abase1 + kk * 16);
        aZ0 = __builtin_amdgcn_mfma_f32_32x32x16_bf16(a0, wvf, aZ0, 0, 0, 0);
        aZ1 = __builtin_amdgcn_mfma_f32_32x32x16_bf16(a1, wvf, aZ1, 0, 0, 0);
    }
    __syncthreads();                 // all P3 atomics complete

    // ---- Phase 4: softmax over k per (g,m) ----
    if (tid < 128) {
        int g = tid >> 6;
        int p = tid & 63;
        float s = lds_s[g][p] * 0.04419417382415922f;   // 1/sqrt(512)
        float mx = s;
        mx = fmaxf(mx, __shfl_xor(mx, 1));
        mx = fmaxf(mx, __shfl_xor(mx, 2));
        mx = fmaxf(mx, __shfl_xor(mx, 4));
        float e = __expf(s - mx);
        float sum = e;
        sum += __shfl_xor(sum, 1);
        sum += __shfl_xor(sum, 2);
        sum += __shfl_xor(sum, 4);
        lds_s[g][p] = e / sum;
    }
    __syncthreads();

    // ---- Phase 5: out[b,m,f] = sum_k P[m,k] Z[b,k,f] + bv[f], in registers ----
    // Z accumulator rows: mrow = (r&3)+8*(r>>2)+4*ahalf = b*8 + kv, so this
    // half holds kv in [4*ahalf, 4*ahalf+4); other half's kv via shfl_xor 32.
    {
        int f = (wave << 5) + arow;
        float bvv = bv[f];
        float* o0 = out + f;
        #pragma unroll
        for (int g = 0; g < 2; ++g) {
            const f32x16& z = g ? aZ1 : aZ0;
            float zs[16];
            #pragma unroll
            for (int r = 0; r < 16; ++r) zs[r] = __shfl_xor(z[r], 32);
            #pragma unroll
            for (int j = 0; j < 4; ++j) {
                int m = j + 4 * ahalf;
                float4 pA = *(const float4*)&lds_s[g][m * 8 + 4 * ahalf];
                float4 pB = *(const float4*)&lds_s[g][m * 8 + 4 * (1 - ahalf)];
                #pragma unroll
                for (int b = 0; b < 4; ++b) {
                    int r0 = 4 * b;
                    float o = pA.x * z[r0]  + pA.y * z[r0 + 1]
                            + pA.z * z[r0 + 2] + pA.w * z[r0 + 3]
                            + pB.x * zs[r0] + pB.y * zs[r0 + 1]
                            + pB.z * zs[r0 + 2] + pB.w * zs[r0 + 3];
                    long base = ((((long)(b * Tt + t)) * Nn + (n0 + g)) * Mm + m) * Dd;
                    o0[base] = o + bvv;
                }
            }
        }
    }
    #undef KOF
}

extern "C" void kernel_launch(void* const* d_in, const int* in_sizes, int n_in,
                              void* d_out, int out_size, void* d_ws, size_t ws_size,
                              hipStream_t stream) {
    const float* x  = (const float*)d_in[0];
    const float* Wq = (const float*)d_in[1];
    const float* bq = (const float*)d_in[2];
    const float* Wk = (const float*)d_in[3];
    const float* Wv = (const float*)d_in[5];
    const float* bv = (const float*)d_in[6];
    float* out = (float*)d_out;
    unsigned short* Wb = (unsigned short*)d_ws;   // B~ (540KB) + Wv (512KB) frags

    pack_kernel<<<512, 256, 0, stream>>>(Wq, Wk, Wv, bq, Wb);
    fused_attn_kernel<<<Tt * Nn / 2, 1024, 0, stream>>>(x, Wb, bv, out);
}